// Round 14
// baseline (299.915 us; speedup 1.0000x reference)
//
#include <hip/hip_runtime.h>
#include <stdint.h>

typedef __attribute__((ext_vector_type(8))) __bf16 bf16x8;
typedef __attribute__((ext_vector_type(4))) float f32x4;

#define MFMA __builtin_amdgcn_mfma_f32_16x16x32_bf16

// fp32 -> bf16 round-to-nearest-even
__device__ __forceinline__ uint16_t f2bf(float f) {
  uint32_t u = __float_as_uint(f);
  return (uint16_t)((u + 0x7fffu + ((u >> 16) & 1u)) >> 16);
}

// fast tanh, clamp-free: 1 - 2/(1+e^{2x}). IEEE-exact at +-inf (inf->1, -inf->-1);
// inputs always finite here. 5 VALU ops.
__device__ __forceinline__ float ftanh(float v) {
  float e = __builtin_amdgcn_exp2f(v * 2.885390081777927f);
  return 1.f - 2.f * __builtin_amdgcn_rcpf(e + 1.f);
}

// async 16B global->LDS (zero staging VGPRs)
__device__ __forceinline__ void gl2lds16(const void* g, void* l) {
  __builtin_amdgcn_global_load_lds(
      (const __attribute__((address_space(1))) unsigned int*)g,
      (__attribute__((address_space(3))) unsigned int*)l, 16, 0, 0);
}

// A-tile LDS addr: row-major [rows][512B], 16B chunks XOR (row&7) (T2).
// Staging writes LINEAR; the XOR is applied to the per-lane global SOURCE.
__device__ __forceinline__ int lds_addr(int row, int chunk) {
  return row * 512 + ((chunk ^ (row & 7)) << 4);
}

// grid-wide barrier: all `target` blocks co-resident (1 block/CU). Counter
// zeroed each kernel_launch via hipMemsetAsync. Release/acquire via threadfence.
__device__ __forceinline__ void gridbar(uint32_t* ctr, uint32_t target) {
  __threadfence();                      // release: this block's writes visible
  __syncthreads();
  if (threadIdx.x == 0) {
    atomicAdd(ctr, 1u);
    while (atomicAdd(ctr, 0u) < target) __builtin_amdgcn_s_sleep(1);
  }
  __syncthreads();
  __threadfence();                      // acquire: drop stale cached lines
}

// 16-cols-per-wave GEMM: NRF*16 out rows x 16 cols; bfrag (32 VGPR) stays resident.
template<int NRF>
__device__ __forceinline__ void gemmN(const uint8_t* base, const bf16x8 bfrag[8],
                                      int l15, int l4, f32x4 acc[NRF]) {
  __builtin_amdgcn_s_setprio(1);
#pragma unroll
  for (int s = 0; s < 8; ++s) {
#pragma unroll
    for (int rf = 0; rf < NRF; ++rf) {
      bf16x8 a = *reinterpret_cast<const bf16x8*>(&base[lds_addr(rf * 16 + l15, s * 4 + l4)]);
      acc[rf] = MFMA(a, bfrag[s], acc[rf], 0, 0, 0);
    }
  }
  __builtin_amdgcn_s_setprio(0);
}

__device__ __forceinline__ void load_bfrag8(const uint16_t* __restrict__ Wbf,
                                            int col, int l4, bf16x8 bfrag[8]) {
#pragma unroll
  for (int s = 0; s < 8; ++s)
    bfrag[s] = *reinterpret_cast<const bf16x8*>(Wbf + col * 256 + s * 32 + l4 * 8);
}

// ---- fused 3/4-level body, 48 KiB LDS (round-13 verified structure) ----
template<bool LEAF, bool FOUR>
__device__ __forceinline__ void fused_body(
    const uint16_t* __restrict__ X,
    const int* __restrict__ pos_idx, const int* __restrict__ wrd_idx,
    const uint16_t* __restrict__ pos_bf, const uint16_t* __restrict__ wrd_bf,
    uint16_t* __restrict__ Y, const uint16_t* __restrict__ Wbf,
    const float* __restrict__ wnp, const int* __restrict__ nidx,
    int off1, int off2, int off3, int off4, int b0, uint8_t* Abuf)
{
  const int tid = threadIdx.x, wv = tid >> 6, lane = tid & 63;
  const int l15 = lane & 15, l4 = lane >> 4;
  const int col = wv * 16 + l15;

  bf16x8 bfrag[8];
  load_bfrag8(Wbf, col, l4, bfrag);

  uint32_t pk1[2][8];

  // ---- L1: two 64-row tiles through Abuf[0:32K) ----
#pragma unroll
  for (int t = 0; t < 2; ++t) {
#pragma unroll
    for (int k = 0; k < 4; ++k) {
      const int ct = tid + k * 512;          // linear LDS chunk [0,2048)
      const int arow = ct >> 5;
      const int c = (ct & 31) ^ (arow & 7);  // pre-swizzled logical chunk
      const void* src;
      if (LEAF) {
        const int seg = c >> 3;              // [posL|wrdL|posR|wrdR]
        const int leaf = 2 * (b0 * 128 + t * 64 + arow) + (seg >> 1);
        const int idx = (seg & 1) ? wrd_idx[leaf] : pos_idx[leaf];
        const uint16_t* tab = (seg & 1) ? wrd_bf : pos_bf;
        src = tab + (size_t)idx * 64 + (c & 7) * 8;
      } else {
        src = X + ((size_t)(b0 * 128 + t * 64 + arow)) * 256 + c * 8;
      }
      gl2lds16(src, &Abuf[ct << 4]);
    }
    __syncthreads();                         // staged

    f32x4 acc[4] = {};
    gemmN<4>(Abuf, bfrag, l15, l4, acc);
#pragma unroll
    for (int rf = 0; rf < 4; ++rf) {
#pragma unroll
      for (int p = 0; p < 2; ++p) {
        const int r1 = t * 64 + rf * 16 + l4 * 4 + 2 * p;
        const int nia = nidx[off1 + b0 * 128 + r1];
        const int nib = nidx[off1 + b0 * 128 + r1 + 1];
        const float va = acc[rf][2 * p]     + wnp[nia * 128 + col];
        const float vb = acc[rf][2 * p + 1] + wnp[nib * 128 + col];
        pk1[t][rf * 2 + p] = (uint32_t)f2bf(ftanh(va)) | ((uint32_t)f2bf(ftanh(vb)) << 16);
      }
    }
    __syncthreads();                         // tile t LDS reads done
  }

  // ---- Mid1 write (128 L1 rows -> 64 A-rows, overlays Abuf[0:32K)) ----
#pragma unroll
  for (int t = 0; t < 2; ++t)
#pragma unroll
    for (int rf = 0; rf < 4; ++rf)
#pragma unroll
      for (int reg = 0; reg < 4; ++reg) {
        const int r1 = t * 64 + rf * 16 + l4 * 4 + reg;
        const int r2 = r1 >> 1;
        const int colA = (r1 & 1) * 128 + col;
        const uint16_t vv = (uint16_t)(pk1[t][rf * 2 + (reg >> 1)] >> ((reg & 1) * 16));
        *reinterpret_cast<uint16_t*>(
            &Abuf[r2 * 512 + (((colA >> 3) ^ (r2 & 7)) << 4) + (colA & 7) * 2]) = vv;
      }
  __syncthreads();                           // Mid1 complete

  // ---- L2: gemm from Mid1; epilogue writes Mid2 [32K,48K) directly ----
  {
    f32x4 acc[4] = {};
    gemmN<4>(Abuf, bfrag, l15, l4, acc);
    uint8_t* Mid2 = Abuf + 32768;
#pragma unroll
    for (int rf = 0; rf < 4; ++rf)
#pragma unroll
      for (int reg = 0; reg < 4; ++reg) {
        const int r2 = rf * 16 + l4 * 4 + reg;          // L2 row [0,64)
        const int ni = nidx[off2 + b0 * 64 + r2];
        const float v = acc[rf][reg] + wnp[ni * 128 + col];
        const int r3 = r2 >> 1;
        const int colA = (r2 & 1) * 128 + col;
        *reinterpret_cast<uint16_t*>(
            &Mid2[r3 * 512 + (((colA >> 3) ^ (r3 & 7)) << 4) + (colA & 7) * 2]) =
            f2bf(ftanh(v));
      }
  }
  __syncthreads();                           // Mid2 complete (+ Mid1 reads done)

  // ---- L3: gemm from Mid2 (32 rows) ----
  {
    f32x4 acc[2] = {};
    gemmN<2>(Abuf + 32768, bfrag, l15, l4, acc);
#pragma unroll
    for (int rf = 0; rf < 2; ++rf)
#pragma unroll
      for (int reg = 0; reg < 4; ++reg) {
        const int row = rf * 16 + l4 * 4 + reg;         // L3 row [0,32)
        const int ni = nidx[off3 + b0 * 32 + row];
        const float v = acc[rf][reg] + wnp[ni * 128 + col];
        if (FOUR) {
          const int r4 = row >> 1;                      // Mid3 A-format [0,8K)
          const int colA = (row & 1) * 128 + col;
          *reinterpret_cast<uint16_t*>(
              &Abuf[r4 * 512 + (((colA >> 3) ^ (r4 & 7)) << 4) + (colA & 7) * 2]) =
              f2bf(ftanh(v));
        } else {
          const int colb = col * 2;                     // OutS natural [0,8K)
          *reinterpret_cast<uint16_t*>(
              &Abuf[row * 256 + (((colb >> 4) ^ (row & 7)) << 4) + (colb & 15)]) =
              f2bf(ftanh(v));
        }
      }
  }
  __syncthreads();                           // Mid3/OutS complete (+ Mid2 reads done)

  if (FOUR) {
    // ---- L4: gemm from Mid3 [0,8K) (16 A-rows); OutS4 -> [32K,36K) ----
    f32x4 acc[1] = {};
    gemmN<1>(Abuf, bfrag, l15, l4, acc);
    uint8_t* OutS4 = Abuf + 32768;
#pragma unroll
    for (int reg = 0; reg < 4; ++reg) {
      const int row = l4 * 4 + reg;                     // L4 row [0,16)
      const int ni = nidx[off4 + b0 * 16 + row];
      const float v = acc[0][reg] + wnp[ni * 128 + col];
      const int colb = col * 2;
      *reinterpret_cast<uint16_t*>(
          &OutS4[row * 256 + (((colb >> 4) ^ (row & 7)) << 4) + (colb & 15)]) =
          f2bf(ftanh(v));
    }
    __syncthreads();
    if (tid < 256) {                         // 16 rows x 256B = 4KB out
      const int i = tid >> 4, c = tid & 15;
      int4 v = *reinterpret_cast<const int4*>(&OutS4[i * 256 + ((c ^ (i & 7)) << 4)]);
      *reinterpret_cast<int4*>(
          reinterpret_cast<uint8_t*>(Y) + ((size_t)b0 * 16 + i) * 256 + c * 16) = v;
    }
    __syncthreads();                         // Abuf safe for reuse by caller
  } else {
    const int i = tid >> 4, c = tid & 15;    // 32 rows x 256B = 8KB out
    int4 v = *reinterpret_cast<const int4*>(&Abuf[i * 256 + ((c ^ (i & 7)) << 4)]);
    *reinterpret_cast<int4*>(
        reinterpret_cast<uint8_t*>(Y) + ((size_t)b0 * 32 + i) * 256 + c * 16) = v;
    __syncthreads();                         // Abuf safe for reuse by caller
  }
}

// ---- tail body: levels n=256..1 (96KB LDS ping-pong, round-13 verified) ----
__device__ __forceinline__ void tail_body(
    const uint16_t* __restrict__ X, const uint16_t* __restrict__ Wbf,
    const float* __restrict__ wnp, const int* __restrict__ nidx,
    int base_off, float* __restrict__ out, uint8_t* P)
{
  const int tid = threadIdx.x, wv = tid >> 6, lane = tid & 63;
  const int l15 = lane & 15, l4 = lane >> 4;
  const int col = wv * 16 + l15;

  bf16x8 bfrag[8];
  load_bfrag8(Wbf, col, l4, bfrag);

  int off = base_off;

  // n=256: A (256 A-rows) from global; Mid (128 A-rows, 64KB) -> P[0]
  for (int t = 0; t < 4; ++t) {
    f32x4 acc[4] = {};
#pragma unroll
    for (int s = 0; s < 8; ++s)
#pragma unroll
      for (int rf = 0; rf < 4; ++rf) {
        bf16x8 a = *reinterpret_cast<const bf16x8*>(
            X + (size_t)(t * 64 + rf * 16 + l15) * 256 + s * 32 + l4 * 8);
        acc[rf] = MFMA(a, bfrag[s], acc[rf], 0, 0, 0);
      }
#pragma unroll
    for (int rf = 0; rf < 4; ++rf)
#pragma unroll
      for (int reg = 0; reg < 4; ++reg) {
        const int r1 = t * 64 + rf * 16 + l4 * 4 + reg;   // [0,256)
        const int ni = nidx[off + r1];
        const float v = acc[rf][reg] + wnp[ni * 128 + col];
        const int r2 = r1 >> 1;
        const int colA = (r1 & 1) * 128 + col;
        *reinterpret_cast<uint16_t*>(
            &P[r2 * 512 + (((colA >> 3) ^ (r2 & 7)) << 4) + (colA & 7) * 2]) =
            f2bf(ftanh(v));
      }
  }
  off += 256;
  __syncthreads();

  int cur = 0;                               // A for n=128 at P[0]
  for (int n = 128; n >= 1; n >>= 1) {
    const uint8_t* Pin = P + (cur ? 65536 : 0);
    uint8_t* Pout = P + (cur ? 0 : 65536);
    const int ntiles = (n + 63) >> 6;
    for (int t = 0; t < ntiles; ++t) {
      f32x4 acc[4] = {};
      gemmN<4>(Pin + t * 32768, bfrag, l15, l4, acc);
#pragma unroll
      for (int rf = 0; rf < 4; ++rf)
#pragma unroll
        for (int reg = 0; reg < 4; ++reg) {
          const int r1 = t * 64 + rf * 16 + l4 * 4 + reg;
          const int rcl = r1 < n ? r1 : n - 1;           // clamp for garbage rows
          const int ni = nidx[off + rcl];
          const float v = acc[rf][reg] + wnp[ni * 128 + col];
          const float y = ftanh(v);
          if (n == 1) {
            if (r1 == 0) out[col] = y;
          } else if (r1 < n) {
            const int r2 = r1 >> 1;
            const int colA = (r1 & 1) * 128 + col;
            *reinterpret_cast<uint16_t*>(
                &Pout[r2 * 512 + (((colA >> 3) ^ (r2 & 7)) << 4) + (colA & 7) * 2]) =
                f2bf(y);
          }
        }
    }
    off += n;
    cur ^= 1;
    __syncthreads();
  }
}

// ---- K1: leaf-gather fused3 (2048 blocks, 48KB LDS) ----
__global__ __launch_bounds__(512, 4)
void leaf_kernel(const int* __restrict__ pos_idx, const int* __restrict__ wrd_idx,
                 const uint16_t* __restrict__ pos_bf, const uint16_t* __restrict__ wrd_bf,
                 uint16_t* __restrict__ Y, const uint16_t* __restrict__ Wbf,
                 const float* __restrict__ wnp, const int* __restrict__ nidx)
{
  __shared__ uint8_t Abuf[49152];
  fused_body<true, false>(nullptr, pos_idx, wrd_idx, pos_bf, wrd_bf,
                          Y, Wbf, wnp, nidx, 0, 262144, 393216, 0,
                          blockIdx.x, Abuf);
}

// ---- rest: L4..L10 + tail in ONE kernel with software grid barriers ----
// 256 blocks x 512 thr x 96KB LDS = exactly 1 block/CU -> all co-resident.
__global__ __launch_bounds__(512, 1)
void rest_kernel(const uint16_t* __restrict__ S1, uint16_t* __restrict__ S2,
                 uint16_t* __restrict__ S4, const uint16_t* __restrict__ Wbf,
                 const float* __restrict__ wnp, const int* __restrict__ nidx,
                 float* __restrict__ out, uint32_t* ctr)
{
  __shared__ uint8_t L[98304];
  const int b0 = blockIdx.x;

  // phase A: L4,L5,L6 (all 256 blocks) S1 -> S2
  fused_body<false, false>(S1, nullptr, nullptr, nullptr, nullptr,
                           S2, Wbf, wnp, nidx, 458752, 491520, 507904, 0, b0, L);
  gridbar(ctr, 256);

  // phase B: L7..L10 (blocks 0..31) S2 -> S4
  if (b0 < 32)
    fused_body<false, true>(S2, nullptr, nullptr, nullptr, nullptr,
                            S4, Wbf, wnp, nidx, 516096, 520192, 522240, 523264, b0, L);
  gridbar(ctr + 64, 256);

  // phase C: tail 256..1 (block 0)
  if (b0 == 0)
    tail_body(S4, Wbf, wnp, nidx, 523776, out, L);
}

// ---- prep: Wc_w/Wpos/Wwrd fp32->bf16; wnp = Wnon + bias (fp32) ----
__global__ void prep_all(const float* __restrict__ Wc_w, const float* __restrict__ Wpos,
                         const float* __restrict__ Wwrd, const float* __restrict__ Wnon,
                         const float* __restrict__ bias,
                         uint16_t* __restrict__ wc_bf, uint16_t* __restrict__ pos_bf,
                         uint16_t* __restrict__ wrd_bf, float* __restrict__ wnp)
{
  int g = blockIdx.x * 256 + threadIdx.x;
  if (g >= 804608) {                          // Wnon + bias -> fp32
    const int idx = g - 804608;               // [0,1024)
    float4 f0 = reinterpret_cast<const float4*>(Wnon)[idx * 2];
    float4 f1 = reinterpret_cast<const float4*>(Wnon)[idx * 2 + 1];
    const int cb = (idx * 8) & 127;
    f0.x += bias[cb];     f0.y += bias[cb + 1]; f0.z += bias[cb + 2]; f0.w += bias[cb + 3];
    f1.x += bias[cb + 4]; f1.y += bias[cb + 5]; f1.z += bias[cb + 6]; f1.w += bias[cb + 7];
    reinterpret_cast<float4*>(wnp)[idx * 2] = f0;
    reinterpret_cast<float4*>(wnp)[idx * 2 + 1] = f1;
    return;
  }
  const float* src; uint16_t* dst; int idx;
  if (g < 4096)      { src = Wc_w; dst = wc_bf;  idx = g; }
  else if (g < 4608) { src = Wpos; dst = pos_bf; idx = g - 4096; }
  else               { src = Wwrd; dst = wrd_bf; idx = g - 4608; }
  float4 f0 = reinterpret_cast<const float4*>(src)[idx * 2];
  float4 f1 = reinterpret_cast<const float4*>(src)[idx * 2 + 1];
  union { int4 v; uint16_t u[8]; } pkv;
  pkv.u[0] = f2bf(f0.x); pkv.u[1] = f2bf(f0.y); pkv.u[2] = f2bf(f0.z); pkv.u[3] = f2bf(f0.w);
  pkv.u[4] = f2bf(f1.x); pkv.u[5] = f2bf(f1.y); pkv.u[6] = f2bf(f1.z); pkv.u[7] = f2bf(f1.w);
  reinterpret_cast<int4*>(dst)[idx] = pkv.v;
}

extern "C" void kernel_launch(void* const* d_in, const int* in_sizes, int n_in,
                              void* d_out, int out_size, void* d_ws, size_t ws_size,
                              hipStream_t stream)
{
  const int*   pos_idx = (const int*)d_in[0];
  const int*   wrd_idx = (const int*)d_in[1];
  const int*   non_idx = (const int*)d_in[2];
  const float* Wwrd    = (const float*)d_in[3];
  const float* Wpos    = (const float*)d_in[4];
  const float* Wnon    = (const float*)d_in[5];
  const float* Wc_w    = (const float*)d_in[6];
  const float* Wc_b    = (const float*)d_in[7];
  float* out = (float*)d_out;

  uint8_t* ws = (uint8_t*)d_ws;
  uint16_t* Wbf    = (uint16_t*)ws;                    // 64 KiB
  uint16_t* pos_bf = (uint16_t*)(ws + 65536);          // 8 KiB
  float*    wnp    = (float*)(ws + 73728);             // 32 KiB (Wnon+bias)
  uint16_t* wrd_bf = (uint16_t*)(ws + 106496);         // 12.8 MB
  uint16_t* S1     = (uint16_t*)(ws + 12906496);       // 16.8 MB (65536x128)
  uint16_t* S2     = (uint16_t*)(ws + 29683712);       // 2.1 MB  (8192x128)
  uint16_t* S4     = (uint16_t*)(ws + 31780864);       // 128 KB  (512x128)
  uint32_t* ctr    = (uint32_t*)(ws + 31912192);       // 512 B barrier counters

  hipMemsetAsync(ctr, 0, 512, stream);

  prep_all<<<3147, 256, 0, stream>>>(Wc_w, Wpos, Wwrd, Wnon, Wc_b,
                                     Wbf, pos_bf, wrd_bf, wnp);

  // Level offsets into non_idx: L1=0(262144), L2=262144(131072), L3=393216(65536),
  // L4=458752(32768), L5=491520(16384), L6=507904(8192), L7=516096(4096),
  // L8=520192(2048), L9=522240(1024), L10=523264(512), tail from 523776(256..1).

  // K1: gather -> L1,L2,L3 -> S1 (65536 rows)
  leaf_kernel<<<2048, 512, 0, stream>>>(pos_idx, wrd_idx, pos_bf, wrd_bf,
                                        S1, Wbf, wnp, non_idx);
  // rest: L4..L10 + tail, one kernel, grid barriers
  rest_kernel<<<256, 512, 0, stream>>>(S1, S2, S4, Wbf, wnp, non_idx, out, ctr);
}

// Round 16
// 245.120 us; speedup vs baseline: 1.2235x; 1.2235x over previous
//
#include <hip/hip_runtime.h>
#include <hip/hip_bf16.h>
#include <stdint.h>

typedef __attribute__((ext_vector_type(8))) __bf16 bf16x8;
typedef __attribute__((ext_vector_type(4))) float f32x4;

#define MFMA __builtin_amdgcn_mfma_f32_16x16x32_bf16

// fp32 -> bf16 round-to-nearest-even (scalar; prep + single stores)
__device__ __forceinline__ uint16_t f2bf(float f) {
  uint32_t u = __float_as_uint(f);
  return (uint16_t)((u + 0x7fffu + ((u >> 16) & 1u)) >> 16);
}

// paired fp32x2 -> bf16x2 via intrinsic (compiler emits v_cvt_pk_bf16_f32)
__device__ __forceinline__ uint32_t pkcvt(float lo, float hi) {
  union { __hip_bfloat162 b; uint32_t u; } cv;
  cv.b = __float22bfloat162_rn(float2{lo, hi});
  return cv.u;
}

// fast tanh, clamp-free: 1 - 2/(1+e^{2x}); IEEE-exact at +-inf; 5 VALU ops
__device__ __forceinline__ float ftanh(float v) {
  float e = __builtin_amdgcn_exp2f(v * 2.885390081777927f);
  return 1.f - 2.f * __builtin_amdgcn_rcpf(e + 1.f);
}

// async 16B global->LDS (zero staging VGPRs)
__device__ __forceinline__ void gl2lds16(const void* g, void* l) {
  __builtin_amdgcn_global_load_lds(
      (const __attribute__((address_space(1))) unsigned int*)g,
      (__attribute__((address_space(3))) unsigned int*)l, 16, 0, 0);
}

// A-tile LDS addr: row-major [rows][512B], 16B chunks XOR (row&7) (T2).
__device__ __forceinline__ int lds_addr(int row, int chunk) {
  return row * 512 + ((chunk ^ (row & 7)) << 4);
}

// grid barrier (all participating blocks co-resident at 1 block/CU).
// Arrival = atomic RMW; POLL = agent-scope atomic LOAD (no RMW storm) + sleep.
__device__ __forceinline__ void gridbar(uint32_t* ctr, uint32_t target) {
  __threadfence();                      // release this block's writes
  __syncthreads();
  if (threadIdx.x == 0) {
    __hip_atomic_fetch_add(ctr, 1u, __ATOMIC_ACQ_REL, __HIP_MEMORY_SCOPE_AGENT);
    while (__hip_atomic_load(ctr, __ATOMIC_ACQUIRE, __HIP_MEMORY_SCOPE_AGENT) < target)
      __builtin_amdgcn_s_sleep(32);     // ~2k cycles backoff
  }
  __syncthreads();
  __threadfence();                      // acquire: drop stale cached lines
}

// 16-cols-per-wave GEMM: NRF*16 out rows x 16 cols; bfrag (32 VGPR) resident.
template<int NRF>
__device__ __forceinline__ void gemmN(const uint8_t* base, const bf16x8 bfrag[8],
                                      int l15, int l4, f32x4 acc[NRF]) {
  __builtin_amdgcn_s_setprio(1);
#pragma unroll
  for (int s = 0; s < 8; ++s) {
#pragma unroll
    for (int rf = 0; rf < NRF; ++rf) {
      bf16x8 a = *reinterpret_cast<const bf16x8*>(&base[lds_addr(rf * 16 + l15, s * 4 + l4)]);
      acc[rf] = MFMA(a, bfrag[s], acc[rf], 0, 0, 0);
    }
  }
  __builtin_amdgcn_s_setprio(0);
}

__device__ __forceinline__ void load_bfrag8(const uint16_t* __restrict__ Wbf,
                                            int col, int l4, bf16x8 bfrag[8]) {
#pragma unroll
  for (int s = 0; s < 8; ++s)
    bfrag[s] = *reinterpret_cast<const bf16x8*>(Wbf + col * 256 + s * 32 + l4 * 8);
}

// ---- fused 3/4-level body, 48 KiB LDS (round-13 verified structure) ----
template<bool LEAF, bool FOUR>
__device__ __forceinline__ void fused_body(
    const uint16_t* __restrict__ X,
    const int* __restrict__ pos_idx, const int* __restrict__ wrd_idx,
    const uint16_t* __restrict__ pos_bf, const uint16_t* __restrict__ wrd_bf,
    uint16_t* __restrict__ Y, const uint16_t* __restrict__ Wbf,
    const float* __restrict__ wnp, const int* __restrict__ nidx,
    int off1, int off2, int off3, int off4, int b0, uint8_t* Abuf)
{
  const int tid = threadIdx.x, wv = tid >> 6, lane = tid & 63;
  const int l15 = lane & 15, l4 = lane >> 4;
  const int col = wv * 16 + l15;

  bf16x8 bfrag[8];
  load_bfrag8(Wbf, col, l4, bfrag);

  uint32_t pk1[2][8];

  // ---- L1: two 64-row tiles through Abuf[0:32K) ----
#pragma unroll
  for (int t = 0; t < 2; ++t) {
#pragma unroll
    for (int k = 0; k < 4; ++k) {
      const int ct = tid + k * 512;          // linear LDS chunk [0,2048)
      const int arow = ct >> 5;
      const int c = (ct & 31) ^ (arow & 7);  // pre-swizzled logical chunk
      const void* src;
      if (LEAF) {
        const int seg = c >> 3;              // [posL|wrdL|posR|wrdR]
        const int leaf = 2 * (b0 * 128 + t * 64 + arow) + (seg >> 1);
        const int idx = (seg & 1) ? wrd_idx[leaf] : pos_idx[leaf];
        const uint16_t* tab = (seg & 1) ? wrd_bf : pos_bf;
        src = tab + (size_t)idx * 64 + (c & 7) * 8;
      } else {
        src = X + ((size_t)(b0 * 128 + t * 64 + arow)) * 256 + c * 8;
      }
      gl2lds16(src, &Abuf[ct << 4]);
    }
    __syncthreads();                         // staged

    f32x4 acc[4] = {};
    gemmN<4>(Abuf, bfrag, l15, l4, acc);
#pragma unroll
    for (int rf = 0; rf < 4; ++rf) {
#pragma unroll
      for (int p = 0; p < 2; ++p) {
        const int r1 = t * 64 + rf * 16 + l4 * 4 + 2 * p;
        const int nia = nidx[off1 + b0 * 128 + r1];
        const int nib = nidx[off1 + b0 * 128 + r1 + 1];
        pk1[t][rf * 2 + p] = pkcvt(ftanh(acc[rf][2 * p]     + wnp[nia * 128 + col]),
                                   ftanh(acc[rf][2 * p + 1] + wnp[nib * 128 + col]));
      }
    }
    __syncthreads();                         // tile t LDS reads done
  }

  // ---- Mid1 write (128 L1 rows -> 64 A-rows, overlays Abuf[0:32K)) ----
#pragma unroll
  for (int t = 0; t < 2; ++t)
#pragma unroll
    for (int rf = 0; rf < 4; ++rf)
#pragma unroll
      for (int reg = 0; reg < 4; ++reg) {
        const int r1 = t * 64 + rf * 16 + l4 * 4 + reg;
        const int r2 = r1 >> 1;
        const int colA = (r1 & 1) * 128 + col;
        const uint16_t vv = (uint16_t)(pk1[t][rf * 2 + (reg >> 1)] >> ((reg & 1) * 16));
        *reinterpret_cast<uint16_t*>(
            &Abuf[r2 * 512 + (((colA >> 3) ^ (r2 & 7)) << 4) + (colA & 7) * 2]) = vv;
      }
  __syncthreads();                           // Mid1 complete

  // ---- L2: gemm from Mid1; epilogue writes Mid2 [32K,48K) directly ----
  {
    f32x4 acc[4] = {};
    gemmN<4>(Abuf, bfrag, l15, l4, acc);
    uint8_t* Mid2 = Abuf + 32768;
#pragma unroll
    for (int rf = 0; rf < 4; ++rf)
#pragma unroll
      for (int reg = 0; reg < 4; ++reg) {
        const int r2 = rf * 16 + l4 * 4 + reg;          // L2 row [0,64)
        const int ni = nidx[off2 + b0 * 64 + r2];
        const float v = acc[rf][reg] + wnp[ni * 128 + col];
        const int r3 = r2 >> 1;
        const int colA = (r2 & 1) * 128 + col;
        *reinterpret_cast<uint16_t*>(
            &Mid2[r3 * 512 + (((colA >> 3) ^ (r3 & 7)) << 4) + (colA & 7) * 2]) =
            f2bf(ftanh(v));
      }
  }
  __syncthreads();                           // Mid2 complete (+ Mid1 reads done)

  // ---- L3: gemm from Mid2 (32 rows) ----
  {
    f32x4 acc[2] = {};
    gemmN<2>(Abuf + 32768, bfrag, l15, l4, acc);
#pragma unroll
    for (int rf = 0; rf < 2; ++rf)
#pragma unroll
      for (int reg = 0; reg < 4; ++reg) {
        const int row = rf * 16 + l4 * 4 + reg;         // L3 row [0,32)
        const int ni = nidx[off3 + b0 * 32 + row];
        const float v = acc[rf][reg] + wnp[ni * 128 + col];
        if (FOUR) {
          const int r4 = row >> 1;                      // Mid3 A-format [0,8K)
          const int colA = (row & 1) * 128 + col;
          *reinterpret_cast<uint16_t*>(
              &Abuf[r4 * 512 + (((colA >> 3) ^ (r4 & 7)) << 4) + (colA & 7) * 2]) =
              f2bf(ftanh(v));
        } else {
          const int colb = col * 2;                     // OutS natural [0,8K)
          *reinterpret_cast<uint16_t*>(
              &Abuf[row * 256 + (((colb >> 4) ^ (row & 7)) << 4) + (colb & 15)]) =
              f2bf(ftanh(v));
        }
      }
  }
  __syncthreads();                           // Mid3/OutS complete (+ Mid2 reads done)

  if (FOUR) {
    // ---- L4: gemm from Mid3 [0,8K) (16 A-rows); OutS4 -> [32K,36K) ----
    f32x4 acc[1] = {};
    gemmN<1>(Abuf, bfrag, l15, l4, acc);
    uint8_t* OutS4 = Abuf + 32768;
#pragma unroll
    for (int reg = 0; reg < 4; ++reg) {
      const int row = l4 * 4 + reg;                     // L4 row [0,16)
      const int ni = nidx[off4 + b0 * 16 + row];
      const float v = acc[0][reg] + wnp[ni * 128 + col];
      const int colb = col * 2;
      *reinterpret_cast<uint16_t*>(
          &OutS4[row * 256 + (((colb >> 4) ^ (row & 7)) << 4) + (colb & 15)]) =
          f2bf(ftanh(v));
    }
    __syncthreads();
    if (tid < 256) {                         // 16 rows x 256B = 4KB out
      const int i = tid >> 4, c = tid & 15;
      int4 v = *reinterpret_cast<const int4*>(&OutS4[i * 256 + ((c ^ (i & 7)) << 4)]);
      *reinterpret_cast<int4*>(
          reinterpret_cast<uint8_t*>(Y) + ((size_t)b0 * 16 + i) * 256 + c * 16) = v;
    }
    __syncthreads();                         // LDS safe for reuse by caller
  } else {
    const int i = tid >> 4, c = tid & 15;    // 32 rows x 256B = 8KB out
    int4 v = *reinterpret_cast<const int4*>(&Abuf[i * 256 + ((c ^ (i & 7)) << 4)]);
    *reinterpret_cast<int4*>(
        reinterpret_cast<uint8_t*>(Y) + ((size_t)b0 * 32 + i) * 256 + c * 16) = v;
    __syncthreads();                         // LDS safe for reuse by caller
  }
}

// ---- tail body: levels n=256..1 (96KB LDS ping-pong, round-13 verified) ----
__device__ __forceinline__ void tail_body(
    const uint16_t* __restrict__ X, const uint16_t* __restrict__ Wbf,
    const float* __restrict__ wnp, const int* __restrict__ nidx,
    int base_off, float* __restrict__ out, uint8_t* P)
{
  const int tid = threadIdx.x, wv = tid >> 6, lane = tid & 63;
  const int l15 = lane & 15, l4 = lane >> 4;
  const int col = wv * 16 + l15;

  bf16x8 bfrag[8];
  load_bfrag8(Wbf, col, l4, bfrag);

  int off = base_off;

  // n=256: A (256 A-rows) from global; Mid (128 A-rows, 64KB) -> P[0]
  for (int t = 0; t < 4; ++t) {
    f32x4 acc[4] = {};
#pragma unroll
    for (int s = 0; s < 8; ++s)
#pragma unroll
      for (int rf = 0; rf < 4; ++rf) {
        bf16x8 a = *reinterpret_cast<const bf16x8*>(
            X + (size_t)(t * 64 + rf * 16 + l15) * 256 + s * 32 + l4 * 8);
        acc[rf] = MFMA(a, bfrag[s], acc[rf], 0, 0, 0);
      }
#pragma unroll
    for (int rf = 0; rf < 4; ++rf)
#pragma unroll
      for (int reg = 0; reg < 4; ++reg) {
        const int r1 = t * 64 + rf * 16 + l4 * 4 + reg;   // [0,256)
        const int ni = nidx[off + r1];
        const float v = acc[rf][reg] + wnp[ni * 128 + col];
        const int r2 = r1 >> 1;
        const int colA = (r1 & 1) * 128 + col;
        *reinterpret_cast<uint16_t*>(
            &P[r2 * 512 + (((colA >> 3) ^ (r2 & 7)) << 4) + (colA & 7) * 2]) =
            f2bf(ftanh(v));
      }
  }
  off += 256;
  __syncthreads();

  int cur = 0;                               // A for n=128 at P[0]
  for (int n = 128; n >= 1; n >>= 1) {
    const uint8_t* Pin = P + (cur ? 65536 : 0);
    uint8_t* Pout = P + (cur ? 0 : 65536);
    const int ntiles = (n + 63) >> 6;
    for (int t = 0; t < ntiles; ++t) {
      f32x4 acc[4] = {};
      gemmN<4>(Pin + t * 32768, bfrag, l15, l4, acc);
#pragma unroll
      for (int rf = 0; rf < 4; ++rf)
#pragma unroll
        for (int reg = 0; reg < 4; ++reg) {
          const int r1 = t * 64 + rf * 16 + l4 * 4 + reg;
          const int rcl = r1 < n ? r1 : n - 1;           // clamp for garbage rows
          const int ni = nidx[off + rcl];
          const float v = acc[rf][reg] + wnp[ni * 128 + col];
          const float y = ftanh(v);
          if (n == 1) {
            if (r1 == 0) out[col] = y;       // rf==0,l4==0,reg==0 lanes of EVERY wave
          } else if (r1 < n) {
            const int r2 = r1 >> 1;
            const int colA = (r1 & 1) * 128 + col;
            *reinterpret_cast<uint16_t*>(
                &Pout[r2 * 512 + (((colA >> 3) ^ (r2 & 7)) << 4) + (colA & 7) * 2]) =
                f2bf(y);
          }
        }
    }
    off += n;
    cur ^= 1;
    __syncthreads();
  }
}

// ---- K1: leaf-gather fused3 (2048 blocks, 48KB LDS) ----
__global__ __launch_bounds__(512, 4)
void leaf_kernel(const int* __restrict__ pos_idx, const int* __restrict__ wrd_idx,
                 const uint16_t* __restrict__ pos_bf, const uint16_t* __restrict__ wrd_bf,
                 uint16_t* __restrict__ Y, const uint16_t* __restrict__ Wbf,
                 const float* __restrict__ wnp, const int* __restrict__ nidx)
{
  __shared__ uint8_t Abuf[49152];
  fused_body<true, false>(nullptr, pos_idx, wrd_idx, pos_bf, wrd_bf,
                          Y, Wbf, wnp, nidx, 0, 262144, 393216, 0,
                          blockIdx.x, Abuf);
}

// ---- rest: L4..L10 + tail in ONE kernel with software grid barriers ----
// 256 blocks x 512 thr x 96KB LDS = exactly 1 block/CU -> all co-resident.
__global__ __launch_bounds__(512, 1)
void rest_kernel(const uint16_t* __restrict__ S1, uint16_t* __restrict__ S2,
                 uint16_t* __restrict__ S4, const uint16_t* __restrict__ Wbf,
                 const float* __restrict__ wnp, const int* __restrict__ nidx,
                 float* __restrict__ out, uint32_t* ctr)
{
  __shared__ uint8_t L[98304];
  const int b0 = blockIdx.x;

  // phase A: L4,L5,L6 (all 256 blocks) S1 -> S2
  fused_body<false, false>(S1, nullptr, nullptr, nullptr, nullptr,
                           S2, Wbf, wnp, nidx, 458752, 491520, 507904, 0, b0, L);
  gridbar(ctr, 256);
  if (b0 >= 32) return;                      // only 32 blocks needed below

  // phase B: L7..L10 (blocks 0..31) S2 -> S4
  fused_body<false, true>(S2, nullptr, nullptr, nullptr, nullptr,
                          S4, Wbf, wnp, nidx, 516096, 520192, 522240, 523264, b0, L);
  gridbar(ctr + 64, 32);                     // barrier among the 32 only
  if (b0 != 0) return;

  // phase C: tail 256..1 (block 0)
  tail_body(S4, Wbf, wnp, nidx, 523776, out, L);
}

// ---- prep: Wc_w/Wpos/Wwrd fp32->bf16; wnp = Wnon + bias; zero barrier ctrs ----
__global__ void prep_all(const float* __restrict__ Wc_w, const float* __restrict__ Wpos,
                         const float* __restrict__ Wwrd, const float* __restrict__ Wnon,
                         const float* __restrict__ bias,
                         uint16_t* __restrict__ wc_bf, uint16_t* __restrict__ pos_bf,
                         uint16_t* __restrict__ wrd_bf, float* __restrict__ wnp,
                         uint32_t* __restrict__ ctr)
{
  if (blockIdx.x == 0 && threadIdx.x < 128) ctr[threadIdx.x] = 0;
  int g = blockIdx.x * 256 + threadIdx.x;
  if (g >= 804608) {                          // Wnon + bias -> fp32
    const int idx = g - 804608;               // [0,1024)
    float4 f0 = reinterpret_cast<const float4*>(Wnon)[idx * 2];
    float4 f1 = reinterpret_cast<const float4*>(Wnon)[idx * 2 + 1];
    const int cb = (idx * 8) & 127;
    f0.x += bias[cb];     f0.y += bias[cb + 1]; f0.z += bias[cb + 2]; f0.w += bias[cb + 3];
    f1.x += bias[cb + 4]; f1.y += bias[cb + 5]; f1.z += bias[cb + 6]; f1.w += bias[cb + 7];
    reinterpret_cast<float4*>(wnp)[idx * 2] = f0;
    reinterpret_cast<float4*>(wnp)[idx * 2 + 1] = f1;
    return;
  }
  const float* src; uint16_t* dst; int idx;
  if (g < 4096)      { src = Wc_w; dst = wc_bf;  idx = g; }
  else if (g < 4608) { src = Wpos; dst = pos_bf; idx = g - 4096; }
  else               { src = Wwrd; dst = wrd_bf; idx = g - 4608; }
  float4 f0 = reinterpret_cast<const float4*>(src)[idx * 2];
  float4 f1 = reinterpret_cast<const float4*>(src)[idx * 2 + 1];
  union { int4 v; uint16_t u[8]; } pkv;
  pkv.u[0] = f2bf(f0.x); pkv.u[1] = f2bf(f0.y); pkv.u[2] = f2bf(f0.z); pkv.u[3] = f2bf(f0.w);
  pkv.u[4] = f2bf(f1.x); pkv.u[5] = f2bf(f1.y); pkv.u[6] = f2bf(f1.z); pkv.u[7] = f2bf(f1.w);
  reinterpret_cast<int4*>(dst)[idx] = pkv.v;
}

extern "C" void kernel_launch(void* const* d_in, const int* in_sizes, int n_in,
                              void* d_out, int out_size, void* d_ws, size_t ws_size,
                              hipStream_t stream)
{
  const int*   pos_idx = (const int*)d_in[0];
  const int*   wrd_idx = (const int*)d_in[1];
  const int*   non_idx = (const int*)d_in[2];
  const float* Wwrd    = (const float*)d_in[3];
  const float* Wpos    = (const float*)d_in[4];
  const float* Wnon    = (const float*)d_in[5];
  const float* Wc_w    = (const float*)d_in[6];
  const float* Wc_b    = (const float*)d_in[7];
  float* out = (float*)d_out;

  uint8_t* ws = (uint8_t*)d_ws;
  uint16_t* Wbf    = (uint16_t*)ws;                    // 64 KiB
  uint16_t* pos_bf = (uint16_t*)(ws + 65536);          // 8 KiB
  float*    wnp    = (float*)(ws + 73728);             // 32 KiB (Wnon+bias)
  uint16_t* wrd_bf = (uint16_t*)(ws + 106496);         // 12.8 MB
  uint16_t* S1     = (uint16_t*)(ws + 12906496);       // 16.8 MB (65536x128)
  uint16_t* S2     = (uint16_t*)(ws + 29683712);       // 2.1 MB  (8192x128)
  uint16_t* S4     = (uint16_t*)(ws + 31780864);       // 128 KB  (512x128)
  uint32_t* ctr    = (uint32_t*)(ws + 31912192);       // 512 B barrier counters

  prep_all<<<3147, 256, 0, stream>>>(Wc_w, Wpos, Wwrd, Wnon, Wc_b,
                                     Wbf, pos_bf, wrd_bf, wnp, ctr);

  // Level offsets into non_idx: L1=0(262144), L2=262144(131072), L3=393216(65536),
  // L4=458752(32768), L5=491520(16384), L6=507904(8192), L7=516096(4096),
  // L8=520192(2048), L9=522240(1024), L10=523264(512), tail from 523776(256..1).

  // K1: gather -> L1,L2,L3 -> S1 (65536 rows)
  leaf_kernel<<<2048, 512, 0, stream>>>(pos_idx, wrd_idx, pos_bf, wrd_bf,
                                        S1, Wbf, wnp, non_idx);
  // rest: L4..L10 + tail, one kernel, fixed grid barriers
  rest_kernel<<<256, 512, 0, stream>>>(S1, S2, S4, Wbf, wnp, non_idx, out, ctr);
}

// Round 17
// 157.970 us; speedup vs baseline: 1.8986x; 1.5517x over previous
//
#include <hip/hip_runtime.h>
#include <hip/hip_bf16.h>
#include <stdint.h>

typedef __attribute__((ext_vector_type(8))) __bf16 bf16x8;
typedef __attribute__((ext_vector_type(4))) float f32x4;

#define MFMA __builtin_amdgcn_mfma_f32_16x16x32_bf16

// fp32 -> bf16 round-to-nearest-even (scalar)
__device__ __forceinline__ uint16_t f2bf(float f) {
  uint32_t u = __float_as_uint(f);
  return (uint16_t)((u + 0x7fffu + ((u >> 16) & 1u)) >> 16);
}

// paired fp32x2 -> bf16x2 via intrinsic (compiler emits v_cvt_pk_bf16_f32)
__device__ __forceinline__ uint32_t pkcvt(float lo, float hi) {
  union { __hip_bfloat162 b; uint32_t u; } cv;
  cv.b = __float22bfloat162_rn(float2{lo, hi});
  return cv.u;
}

// fast tanh, clamp-free: 1 - 2/(1+e^{2x}); IEEE-exact at +-inf; 5 VALU ops
__device__ __forceinline__ float ftanh(float v) {
  float e = __builtin_amdgcn_exp2f(v * 2.885390081777927f);
  return 1.f - 2.f * __builtin_amdgcn_rcpf(e + 1.f);
}

// async 16B global->LDS (zero staging VGPRs)
__device__ __forceinline__ void gl2lds16(const void* g, void* l) {
  __builtin_amdgcn_global_load_lds(
      (const __attribute__((address_space(1))) unsigned int*)g,
      (__attribute__((address_space(3))) unsigned int*)l, 16, 0, 0);
}

// A-tile LDS addr: row-major [rows][512B], 16B chunks XOR (row&7) (T2).
// Staging writes LINEAR; the XOR is applied to the per-lane global SOURCE.
__device__ __forceinline__ int lds_addr(int row, int chunk) {
  return row * 512 + ((chunk ^ (row & 7)) << 4);
}

// 16-cols-per-wave GEMM: NRF*16 out rows x 16 cols; bfrag (32 VGPR) resident.
template<int NRF>
__device__ __forceinline__ void gemmN(const uint8_t* base, const bf16x8 bfrag[8],
                                      int l15, int l4, f32x4 acc[NRF]) {
  __builtin_amdgcn_s_setprio(1);
#pragma unroll
  for (int s = 0; s < 8; ++s) {
#pragma unroll
    for (int rf = 0; rf < NRF; ++rf) {
      bf16x8 a = *reinterpret_cast<const bf16x8*>(&base[lds_addr(rf * 16 + l15, s * 4 + l4)]);
      acc[rf] = MFMA(a, bfrag[s], acc[rf], 0, 0, 0);
    }
  }
  __builtin_amdgcn_s_setprio(0);
}

__device__ __forceinline__ void load_bfrag8(const uint16_t* __restrict__ Wbf,
                                            int col, int l4, bf16x8 bfrag[8]) {
#pragma unroll
  for (int s = 0; s < 8; ++s)
    bfrag[s] = *reinterpret_cast<const bf16x8*>(Wbf + col * 256 + s * 32 + l4 * 8);
}

// ---- fused 3/4-level kernel, 48 KiB LDS (round-13 structure + r16 epilogue) ----
// Block b0: 256 inputs -> 128 L1 rows (2 tiles) -> 64 -> 32 (-> 16) output rows.
// Regions: A/Mid1 [0,32K); Mid2 [32K,48K); FOUR=false: OutS [0,8K);
//          FOUR=true:  Mid3 [0,8K), OutS4 [32K,36K).
template<bool LEAF, bool FOUR>
__global__ __launch_bounds__(512, 4)
void fused_kernel(const uint16_t* __restrict__ X,
                  const int* __restrict__ pos_idx, const int* __restrict__ wrd_idx,
                  const uint16_t* __restrict__ pos_bf, const uint16_t* __restrict__ wrd_bf,
                  uint16_t* __restrict__ Y, const uint16_t* __restrict__ Wbf,
                  const float* __restrict__ wnp,
                  const int* __restrict__ nidx, int off1, int off2, int off3, int off4)
{
  __shared__ uint8_t Abuf[49152];
  const int tid = threadIdx.x, wv = tid >> 6, lane = tid & 63;
  const int l15 = lane & 15, l4 = lane >> 4;
  const int col = wv * 16 + l15;
  const int b0 = blockIdx.x;

  bf16x8 bfrag[8];
  load_bfrag8(Wbf, col, l4, bfrag);

  uint32_t pk1[2][8];

  // ---- L1: two 64-row tiles through Abuf[0:32K) ----
#pragma unroll
  for (int t = 0; t < 2; ++t) {
#pragma unroll
    for (int k = 0; k < 4; ++k) {
      const int ct = tid + k * 512;          // linear LDS chunk [0,2048)
      const int arow = ct >> 5;
      const int c = (ct & 31) ^ (arow & 7);  // pre-swizzled logical chunk
      const void* src;
      if (LEAF) {
        const int seg = c >> 3;              // [posL|wrdL|posR|wrdR]
        const int leaf = 2 * (b0 * 128 + t * 64 + arow) + (seg >> 1);
        const int idx = (seg & 1) ? wrd_idx[leaf] : pos_idx[leaf];
        const uint16_t* tab = (seg & 1) ? wrd_bf : pos_bf;
        src = tab + (size_t)idx * 64 + (c & 7) * 8;
      } else {
        src = X + ((size_t)(b0 * 128 + t * 64 + arow)) * 256 + c * 8;
      }
      gl2lds16(src, &Abuf[ct << 4]);
    }
    __syncthreads();                         // staged

    f32x4 acc[4] = {};
    gemmN<4>(Abuf, bfrag, l15, l4, acc);
#pragma unroll
    for (int rf = 0; rf < 4; ++rf) {
#pragma unroll
      for (int p = 0; p < 2; ++p) {
        const int r1 = t * 64 + rf * 16 + l4 * 4 + 2 * p;
        const int nia = nidx[off1 + b0 * 128 + r1];
        const int nib = nidx[off1 + b0 * 128 + r1 + 1];
        pk1[t][rf * 2 + p] = pkcvt(ftanh(acc[rf][2 * p]     + wnp[nia * 128 + col]),
                                   ftanh(acc[rf][2 * p + 1] + wnp[nib * 128 + col]));
      }
    }
    __syncthreads();                         // tile t LDS reads done
  }

  // ---- Mid1 write (128 L1 rows -> 64 A-rows, overlays Abuf[0:32K)) ----
#pragma unroll
  for (int t = 0; t < 2; ++t)
#pragma unroll
    for (int rf = 0; rf < 4; ++rf)
#pragma unroll
      for (int reg = 0; reg < 4; ++reg) {
        const int r1 = t * 64 + rf * 16 + l4 * 4 + reg;
        const int r2 = r1 >> 1;
        const int colA = (r1 & 1) * 128 + col;
        const uint16_t vv = (uint16_t)(pk1[t][rf * 2 + (reg >> 1)] >> ((reg & 1) * 16));
        *reinterpret_cast<uint16_t*>(
            &Abuf[r2 * 512 + (((colA >> 3) ^ (r2 & 7)) << 4) + (colA & 7) * 2]) = vv;
      }
  __syncthreads();                           // Mid1 complete

  // ---- L2: gemm from Mid1; epilogue writes Mid2 [32K,48K) directly ----
  {
    f32x4 acc[4] = {};
    gemmN<4>(Abuf, bfrag, l15, l4, acc);
    uint8_t* Mid2 = Abuf + 32768;
#pragma unroll
    for (int rf = 0; rf < 4; ++rf)
#pragma unroll
      for (int reg = 0; reg < 4; ++reg) {
        const int r2 = rf * 16 + l4 * 4 + reg;          // L2 row [0,64)
        const int ni = nidx[off2 + b0 * 64 + r2];
        const float v = acc[rf][reg] + wnp[ni * 128 + col];
        const int r3 = r2 >> 1;
        const int colA = (r2 & 1) * 128 + col;
        *reinterpret_cast<uint16_t*>(
            &Mid2[r3 * 512 + (((colA >> 3) ^ (r3 & 7)) << 4) + (colA & 7) * 2]) =
            f2bf(ftanh(v));
      }
  }
  __syncthreads();                           // Mid2 complete (+ Mid1 reads done)

  // ---- L3: gemm from Mid2 (32 rows) ----
  {
    f32x4 acc[2] = {};
    gemmN<2>(Abuf + 32768, bfrag, l15, l4, acc);
#pragma unroll
    for (int rf = 0; rf < 2; ++rf)
#pragma unroll
      for (int reg = 0; reg < 4; ++reg) {
        const int row = rf * 16 + l4 * 4 + reg;         // L3 row [0,32)
        const int ni = nidx[off3 + b0 * 32 + row];
        const float v = acc[rf][reg] + wnp[ni * 128 + col];
        if (FOUR) {
          const int r4 = row >> 1;                      // Mid3 A-format [0,8K)
          const int colA = (row & 1) * 128 + col;
          *reinterpret_cast<uint16_t*>(
              &Abuf[r4 * 512 + (((colA >> 3) ^ (r4 & 7)) << 4) + (colA & 7) * 2]) =
              f2bf(ftanh(v));
        } else {
          const int colb = col * 2;                     // OutS natural [0,8K)
          *reinterpret_cast<uint16_t*>(
              &Abuf[row * 256 + (((colb >> 4) ^ (row & 7)) << 4) + (colb & 15)]) =
              f2bf(ftanh(v));
        }
      }
  }
  __syncthreads();                           // Mid3/OutS complete (+ Mid2 reads done)

  if (FOUR) {
    // ---- L4: gemm from Mid3 [0,8K) (16 A-rows); OutS4 -> [32K,36K) ----
    f32x4 acc[1] = {};
    gemmN<1>(Abuf, bfrag, l15, l4, acc);
    uint8_t* OutS4 = Abuf + 32768;
#pragma unroll
    for (int reg = 0; reg < 4; ++reg) {
      const int row = l4 * 4 + reg;                     // L4 row [0,16)
      const int ni = nidx[off4 + b0 * 16 + row];
      const float v = acc[0][reg] + wnp[ni * 128 + col];
      const int colb = col * 2;
      *reinterpret_cast<uint16_t*>(
          &OutS4[row * 256 + (((colb >> 4) ^ (row & 7)) << 4) + (colb & 15)]) =
          f2bf(ftanh(v));
    }
    __syncthreads();
    if (tid < 256) {                         // 16 rows x 256B = 4KB out
      const int i = tid >> 4, c = tid & 15;
      int4 v = *reinterpret_cast<const int4*>(&OutS4[i * 256 + ((c ^ (i & 7)) << 4)]);
      *reinterpret_cast<int4*>(
          reinterpret_cast<uint8_t*>(Y) + ((size_t)b0 * 16 + i) * 256 + c * 16) = v;
    }
  } else {
    const int i = tid >> 4, c = tid & 15;    // 32 rows x 256B = 8KB out
    int4 v = *reinterpret_cast<const int4*>(&Abuf[i * 256 + ((c ^ (i & 7)) << 4)]);
    *reinterpret_cast<int4*>(
        reinterpret_cast<uint8_t*>(Y) + ((size_t)b0 * 32 + i) * 256 + c * 16) = v;
  }
}

// ---- tail: levels n=256..1 in ONE block (round-13 version, new ftanh) ----
__global__ __launch_bounds__(512, 1)
void tail_kernel(const uint16_t* __restrict__ X, const uint16_t* __restrict__ Wbf,
                 const float* __restrict__ wnp,
                 const int* __restrict__ nidx, int base_off, float* __restrict__ out)
{
  __shared__ uint8_t P[98304];   // ping-pong: A @0 (<=64KB) / @65536 (<=32KB)
  const int tid = threadIdx.x, wv = tid >> 6, lane = tid & 63;
  const int l15 = lane & 15, l4 = lane >> 4;
  const int col = wv * 16 + l15;

  bf16x8 bfrag[8];
  load_bfrag8(Wbf, col, l4, bfrag);

  int off = base_off;

  // n=256: A (256 A-rows) from global; Mid (128 A-rows, 64KB) -> P[0]
  for (int t = 0; t < 4; ++t) {
    f32x4 acc[4] = {};
#pragma unroll
    for (int s = 0; s < 8; ++s)
#pragma unroll
      for (int rf = 0; rf < 4; ++rf) {
        bf16x8 a = *reinterpret_cast<const bf16x8*>(
            X + (size_t)(t * 64 + rf * 16 + l15) * 256 + s * 32 + l4 * 8);
        acc[rf] = MFMA(a, bfrag[s], acc[rf], 0, 0, 0);
      }
#pragma unroll
    for (int rf = 0; rf < 4; ++rf)
#pragma unroll
      for (int reg = 0; reg < 4; ++reg) {
        const int r1 = t * 64 + rf * 16 + l4 * 4 + reg;   // [0,256)
        const int ni = nidx[off + r1];
        const float v = acc[rf][reg] + wnp[ni * 128 + col];
        const int r2 = r1 >> 1;
        const int colA = (r1 & 1) * 128 + col;
        *reinterpret_cast<uint16_t*>(
            &P[r2 * 512 + (((colA >> 3) ^ (r2 & 7)) << 4) + (colA & 7) * 2]) =
            f2bf(ftanh(v));
      }
  }
  off += 256;
  __syncthreads();

  int cur = 0;                               // A for n=128 at P[0]
  for (int n = 128; n >= 1; n >>= 1) {
    const uint8_t* Pin = P + (cur ? 65536 : 0);
    uint8_t* Pout = P + (cur ? 0 : 65536);
    const int ntiles = (n + 63) >> 6;
    for (int t = 0; t < ntiles; ++t) {
      f32x4 acc[4] = {};
      gemmN<4>(Pin + t * 32768, bfrag, l15, l4, acc);
#pragma unroll
      for (int rf = 0; rf < 4; ++rf)
#pragma unroll
        for (int reg = 0; reg < 4; ++reg) {
          const int r1 = t * 64 + rf * 16 + l4 * 4 + reg;
          const int rcl = r1 < n ? r1 : n - 1;           // clamp for garbage rows
          const int ni = nidx[off + rcl];
          const float v = acc[rf][reg] + wnp[ni * 128 + col];
          const float y = ftanh(v);
          if (n == 1) {
            if (r1 == 0) out[col] = y;
          } else if (r1 < n) {
            const int r2 = r1 >> 1;
            const int colA = (r1 & 1) * 128 + col;
            *reinterpret_cast<uint16_t*>(
                &Pout[r2 * 512 + (((colA >> 3) ^ (r2 & 7)) << 4) + (colA & 7) * 2]) =
                f2bf(y);
          }
        }
    }
    off += n;
    cur ^= 1;
    __syncthreads();
  }
}

// ---- prep: Wc_w/Wpos/Wwrd fp32->bf16; wnp = Wnon + bias (fp32) ----
__global__ void prep_all(const float* __restrict__ Wc_w, const float* __restrict__ Wpos,
                         const float* __restrict__ Wwrd, const float* __restrict__ Wnon,
                         const float* __restrict__ bias,
                         uint16_t* __restrict__ wc_bf, uint16_t* __restrict__ pos_bf,
                         uint16_t* __restrict__ wrd_bf, float* __restrict__ wnp)
{
  int g = blockIdx.x * 256 + threadIdx.x;
  if (g >= 804608) {                          // Wnon + bias -> fp32
    const int idx = g - 804608;               // [0,1024)
    float4 f0 = reinterpret_cast<const float4*>(Wnon)[idx * 2];
    float4 f1 = reinterpret_cast<const float4*>(Wnon)[idx * 2 + 1];
    const int cb = (idx * 8) & 127;
    f0.x += bias[cb];     f0.y += bias[cb + 1]; f0.z += bias[cb + 2]; f0.w += bias[cb + 3];
    f1.x += bias[cb + 4]; f1.y += bias[cb + 5]; f1.z += bias[cb + 6]; f1.w += bias[cb + 7];
    reinterpret_cast<float4*>(wnp)[idx * 2] = f0;
    reinterpret_cast<float4*>(wnp)[idx * 2 + 1] = f1;
    return;
  }
  const float* src; uint16_t* dst; int idx;
  if (g < 4096)      { src = Wc_w; dst = wc_bf;  idx = g; }
  else if (g < 4608) { src = Wpos; dst = pos_bf; idx = g - 4096; }
  else               { src = Wwrd; dst = wrd_bf; idx = g - 4608; }
  float4 f0 = reinterpret_cast<const float4*>(src)[idx * 2];
  float4 f1 = reinterpret_cast<const float4*>(src)[idx * 2 + 1];
  union { int4 v; uint16_t u[8]; } pkv;
  pkv.u[0] = f2bf(f0.x); pkv.u[1] = f2bf(f0.y); pkv.u[2] = f2bf(f0.z); pkv.u[3] = f2bf(f0.w);
  pkv.u[4] = f2bf(f1.x); pkv.u[5] = f2bf(f1.y); pkv.u[6] = f2bf(f1.z); pkv.u[7] = f2bf(f1.w);
  reinterpret_cast<int4*>(dst)[idx] = pkv.v;
}

extern "C" void kernel_launch(void* const* d_in, const int* in_sizes, int n_in,
                              void* d_out, int out_size, void* d_ws, size_t ws_size,
                              hipStream_t stream)
{
  const int*   pos_idx = (const int*)d_in[0];
  const int*   wrd_idx = (const int*)d_in[1];
  const int*   non_idx = (const int*)d_in[2];
  const float* Wwrd    = (const float*)d_in[3];
  const float* Wpos    = (const float*)d_in[4];
  const float* Wnon    = (const float*)d_in[5];
  const float* Wc_w    = (const float*)d_in[6];
  const float* Wc_b    = (const float*)d_in[7];
  float* out = (float*)d_out;

  uint8_t* ws = (uint8_t*)d_ws;
  uint16_t* Wbf    = (uint16_t*)ws;                    // 64 KiB
  uint16_t* pos_bf = (uint16_t*)(ws + 65536);          // 8 KiB
  float*    wnp    = (float*)(ws + 73728);             // 32 KiB (Wnon+bias)
  uint16_t* wrd_bf = (uint16_t*)(ws + 106496);         // 12.8 MB
  uint16_t* S1     = (uint16_t*)(ws + 12906496);       // 16.8 MB (65536x128)
  uint16_t* S2     = (uint16_t*)(ws + 29683712);       // 2.1 MB  (8192x128)
  uint16_t* S4     = (uint16_t*)(ws + 31780864);       // 128 KB  (512x128)

  prep_all<<<3147, 256, 0, stream>>>(Wc_w, Wpos, Wwrd, Wnon, Wc_b,
                                     Wbf, pos_bf, wrd_bf, wnp);

  // Level offsets into non_idx: L1=0(262144), L2=262144(131072), L3=393216(65536),
  // L4=458752(32768), L5=491520(16384), L6=507904(8192), L7=516096(4096),
  // L8=520192(2048), L9=522240(1024), L10=523264(512), tail from 523776(256..1).

  // K1: gather -> L1,L2,L3 -> S1 (65536 rows)
  fused_kernel<true, false><<<2048, 512, 0, stream>>>(
      nullptr, pos_idx, wrd_idx, pos_bf, wrd_bf, S1, Wbf, wnp, non_idx,
      0, 262144, 393216, 0);
  // K2: S1 -> L4,L5,L6 -> S2 (8192 rows)
  fused_kernel<false, false><<<256, 512, 0, stream>>>(
      S1, nullptr, nullptr, nullptr, nullptr, S2, Wbf, wnp, non_idx,
      458752, 491520, 507904, 0);
  // K3: S2 -> L7,L8,L9,L10 -> S4 (512 rows)
  fused_kernel<false, true><<<32, 512, 0, stream>>>(
      S2, nullptr, nullptr, nullptr, nullptr, S4, Wbf, wnp, non_idx,
      516096, 520192, 522240, 523264);
  // tail: 256..1 (reads 512 rows in S4)
  tail_kernel<<<1, 512, 0, stream>>>(S4, Wbf, wnp, non_idx, 523776, out);
}